// Round 8
// baseline (66.843 us; speedup 1.0000x reference)
//
#include <hip/hip_runtime.h>
#include <hip/hip_cooperative_groups.h>

namespace cg = cooperative_groups;

// Segment-sum via gather (round 8).
// History: r1 scatter-atomics 449us -> r2 hist+gather 43.3 -> r3 NT-everything
// 49.7 REVERTED -> r4 reg-prefetch slots 42.7 BEST -> r5 fused persistent coop
// 197 REVERTED -> r6 2-blk/seg 43.9 NEUTRAL -> r7 NT store 43.0 NEUTRAL.
// r8: (a) {zero,hist} fused into ONE small cooperative kernel (128 blocks;
// cheap grid.sync) -> 2 in-graph dispatches; (b) count merged into slot
// record header: 64B/seg = [u32 k][u16 slots x30]; gather's index fetch is a
// single 16B load giving k + 6 ids (k<=6 covers 99.6% of Poisson(2) segs).

#define CAP 30          // slots per record; P(k>30 | lambda=2) ~ 1e-24
#define DDIM 1024
#define RECB 64         // bytes per segment record

typedef __attribute__((ext_vector_type(4))) float f4;
typedef __attribute__((ext_vector_type(4))) int i4;

__device__ __forceinline__ void acc_pair(const float* __restrict__ data,
                                         int pair, int base, int k, int col,
                                         f4& acc) {
    int r0 = pair & 0xFFFF;
    int r1 = (pair >> 16) & 0xFFFF;
    if (base < k)
        acc += *reinterpret_cast<const f4*>(data + (long)r0 * DDIM + col);
    if (base + 1 < k)
        acc += *reinterpret_cast<const f4*>(data + (long)r1 * DDIM + col);
}

// Fused {zero headers, grid.sync, histogram} — small cooperative kernel.
__global__ void zero_hist(const int* __restrict__ tags, int n_rows, int n_seg,
                          char* __restrict__ recs) {
    cg::grid_group grid = cg::this_grid();
    int tid = blockIdx.x * blockDim.x + threadIdx.x;
    int nth = gridDim.x * blockDim.x;

    for (int s = tid; s < n_seg; s += nth)
        *reinterpret_cast<int*>(recs + (long)s * RECB) = 0;
    grid.sync();

    for (int r = tid; r < n_rows; r += nth) {
        int t = tags[r];
        int* hdr = reinterpret_cast<int*>(recs + (long)t * RECB);
        int pos = atomicAdd(hdr, 1);
        if (pos < CAP)
            reinterpret_cast<unsigned short*>(hdr)[2 + pos] = (unsigned short)r;
    }
}

// Non-cooperative fallback pieces.
__global__ void zero_hdrs(char* __restrict__ recs, int n_seg) {
    int s = blockIdx.x * blockDim.x + threadIdx.x;
    if (s < n_seg) *reinterpret_cast<int*>(recs + (long)s * RECB) = 0;
}
__global__ void hist_fill(const int* __restrict__ tags, int n_rows,
                          char* __restrict__ recs) {
    int r = blockIdx.x * blockDim.x + threadIdx.x;
    if (r < n_rows) {
        int t = tags[r];
        int* hdr = reinterpret_cast<int*>(recs + (long)t * RECB);
        int pos = atomicAdd(hdr, 1);
        if (pos < CAP)
            reinterpret_cast<unsigned short*>(hdr)[2 + pos] = (unsigned short)r;
    }
}

__global__ void gather_sum(const float* __restrict__ data,
                           const int* __restrict__ tags,
                           const char* __restrict__ recs,
                           float* __restrict__ out,
                           int n_rows) {
    int s = blockIdx.x;                 // one block per output segment
    int col = threadIdx.x * 4;          // 256 threads x float4 = 1024 cols

    const i4* rec = reinterpret_cast<const i4*>(recs + (long)s * RECB);
    i4 w0 = rec[0];                     // ONE load: k + slots[0..5]
    int k = w0[0];

    f4 acc = {0.f, 0.f, 0.f, 0.f};
    if (k <= 6) {                       // 99.6% of segments
        acc_pair(data, w0[1], 0, k, col, acc);
        acc_pair(data, w0[2], 2, k, col, acc);
        acc_pair(data, w0[3], 4, k, col, acc);
    } else if (k <= CAP) {
        acc_pair(data, w0[1], 0, k, col, acc);
        acc_pair(data, w0[2], 2, k, col, acc);
        acc_pair(data, w0[3], 4, k, col, acc);
        i4 w1 = rec[1], w2 = rec[2], w3 = rec[3];
        #pragma unroll
        for (int e = 0; e < 4; ++e) acc_pair(data, w1[e], 6 + 2 * e, k, col, acc);
        #pragma unroll
        for (int e = 0; e < 4; ++e) acc_pair(data, w2[e], 14 + 2 * e, k, col, acc);
        #pragma unroll
        for (int e = 0; e < 4; ++e) acc_pair(data, w3[e], 22 + 2 * e, k, col, acc);
    } else {
        // Overflow fallback (deterministic, essentially never taken).
        for (int r = 0; r < n_rows; ++r) {
            if (tags[r] == s)
                acc += *reinterpret_cast<const f4*>(data + (long)r * DDIM + col);
        }
    }
    // out is write-once, never re-read in-graph: stream past the caches.
    __builtin_nontemporal_store(acc, reinterpret_cast<f4*>(out + (long)s * DDIM + col));
}

// Safety-net scatter kernel (used only if ws_size is too small for the index).
__global__ void combine_scatter_add(const float* __restrict__ data,
                                    const int* __restrict__ tags,
                                    float* __restrict__ out,
                                    long total_elems) {
    long stride = (long)gridDim.x * blockDim.x * 4L;
    for (long i = ((long)blockIdx.x * blockDim.x + threadIdx.x) * 4L;
         i < total_elems; i += stride) {
        float4 v = *reinterpret_cast<const float4*>(data + i);
        long row = i >> 10;
        int col = (int)(i & 1023);
        int tag = tags[row];
        float* dst = out + ((long)tag << 10) + col;
        atomicAdd(dst + 0, v.x);
        atomicAdd(dst + 1, v.y);
        atomicAdd(dst + 2, v.z);
        atomicAdd(dst + 3, v.w);
    }
}

extern "C" void kernel_launch(void* const* d_in, const int* in_sizes, int n_in,
                              void* d_out, int out_size, void* d_ws, size_t ws_size,
                              hipStream_t stream) {
    const float* data = (const float*)d_in[0];
    const int* tags = (const int*)d_in[1];
    float* out = (float*)d_out;

    long total = (long)in_sizes[0];   // 33554432
    int n_rows = in_sizes[1];         // 32768
    int n_seg = out_size / DDIM;      // 16384

    size_t recs_bytes = (size_t)n_seg * RECB;   // 1 MiB

    if (ws_size < recs_bytes) {
        hipMemsetAsync(d_out, 0, (size_t)out_size * sizeof(float), stream);
        combine_scatter_add<<<2048, 256, 0, stream>>>(data, tags, out, total);
        return;
    }

    char* recs = (char*)d_ws;

    void* args[] = {(void*)&tags, (void*)&n_rows, (void*)&n_seg, (void*)&recs};
    hipError_t err = hipLaunchCooperativeKernel(
        reinterpret_cast<const void*>(&zero_hist),
        dim3(128), dim3(256), args, 0, stream);
    if (err != hipSuccess) {
        // Fallback: separate zero + hist dispatches.
        zero_hdrs<<<(n_seg + 255) / 256, 256, 0, stream>>>(recs, n_seg);
        hist_fill<<<(n_rows + 255) / 256, 256, 0, stream>>>(tags, n_rows, recs);
    }

    gather_sum<<<n_seg, 256, 0, stream>>>(data, tags, recs, out, n_rows);
}

// Round 9
// 42.969 us; speedup vs baseline: 1.5556x; 1.5556x over previous
//
#include <hip/hip_runtime.h>

// Segment-sum via gather — FINAL (restore of round-4 best, 42.7us).
// History: r1 scatter-atomics 449us (L2-atomic-bound) -> r2 hist+gather 43.3
// -> r3 NT-everything 49.7 REVERTED (data reads are L3-served; NT bypassed L3)
// -> r4 reg-prefetched slots 42.7 BEST -> r5 fused persistent cooperative 197
// REVERTED (persistent blocks serialize; cooperative nodes cost in graphs)
// -> r6 2-blk/seg 43.9 NEUTRAL (BW-bound, not latency-bound) -> r7 NT store
// 43.0 NEUTRAL -> r8 coop zero_hist + merged 64B records 66.8 REVERTED
// (coop-in-graph overhead + atomic/store same-cacheline serialization).
// Four independent structures cluster at 42.7-43.9us with traffic at the
// mandatory minimum -> practical roofline; this is the best-measured form.

#define CAP 32          // slot capacity per segment; Poisson(2) tail beyond 32 ~ 1e-26
#define N_SEG 16384
#define DDIM 1024

typedef __attribute__((ext_vector_type(4))) float f4;
typedef __attribute__((ext_vector_type(4))) int i4;

__global__ void hist_fill(const int* __restrict__ tags, int n_rows,
                          int* __restrict__ counts,
                          unsigned short* __restrict__ slots) {
    int r = blockIdx.x * blockDim.x + threadIdx.x;
    if (r < n_rows) {
        int t = tags[r];
        int pos = atomicAdd(&counts[t], 1);
        if (pos < CAP) slots[(long)t * CAP + pos] = (unsigned short)r;
    }
}

__global__ void gather_sum(const float* __restrict__ data,
                           const int* __restrict__ tags,
                           const int* __restrict__ counts,
                           const unsigned short* __restrict__ slots,
                           float* __restrict__ out,
                           int n_rows) {
    int s = blockIdx.x;                 // segment id, one block per output row
    int col = threadIdx.x * 4;          // 256 threads x float4 = 1024 cols
    int k = counts[s];
    f4 acc = {0.f, 0.f, 0.f, 0.f};

    if (k <= CAP) {
        // Slot list: 32 u16 = 64B = 4 i4 words, 8 ids/word, prefetched to regs
        // so the up-to-8 data loads per word issue independently.
        const i4* sp = reinterpret_cast<const i4*>(slots + (long)s * CAP);
        int done = 0;
        #pragma unroll
        for (int w = 0; w < 4; ++w) {
            if (done >= k) break;                   // wave-uniform
            i4 word = sp[w];
            #pragma unroll
            for (int e = 0; e < 4; ++e) {
                int pair = word[e];
                int r0 = pair & 0xFFFF;
                int r1 = (pair >> 16) & 0xFFFF;
                if (done < k) {
                    acc += *reinterpret_cast<const f4*>(data + (long)r0 * DDIM + col);
                    ++done;
                }
                if (done < k) {
                    acc += *reinterpret_cast<const f4*>(data + (long)r1 * DDIM + col);
                    ++done;
                }
            }
        }
    } else {
        // Overflow fallback (deterministic, essentially never taken): slots
        // hold an arbitrary subset, so recompute the whole segment by scanning
        // all tags (L2-resident broadcast reads).
        for (int r = 0; r < n_rows; ++r) {
            if (tags[r] == s) {
                acc += *reinterpret_cast<const f4*>(data + (long)r * DDIM + col);
            }
        }
    }
    *reinterpret_cast<f4*>(out + (long)s * DDIM + col) = acc;
}

// Safety-net scatter kernel (used only if ws_size is too small for the index).
__global__ void combine_scatter_add(const float* __restrict__ data,
                                    const int* __restrict__ tags,
                                    float* __restrict__ out,
                                    long total_elems) {
    long stride = (long)gridDim.x * blockDim.x * 4L;
    for (long i = ((long)blockIdx.x * blockDim.x + threadIdx.x) * 4L;
         i < total_elems; i += stride) {
        float4 v = *reinterpret_cast<const float4*>(data + i);
        long row = i >> 10;
        int col = (int)(i & 1023);
        int tag = tags[row];
        float* dst = out + ((long)tag << 10) + col;
        atomicAdd(dst + 0, v.x);
        atomicAdd(dst + 1, v.y);
        atomicAdd(dst + 2, v.z);
        atomicAdd(dst + 3, v.w);
    }
}

extern "C" void kernel_launch(void* const* d_in, const int* in_sizes, int n_in,
                              void* d_out, int out_size, void* d_ws, size_t ws_size,
                              hipStream_t stream) {
    const float* data = (const float*)d_in[0];
    const int* tags = (const int*)d_in[1];
    float* out = (float*)d_out;

    long total = (long)in_sizes[0];   // 33554432
    int n_rows = in_sizes[1];         // 32768

    size_t counts_bytes = (size_t)N_SEG * sizeof(int);                 // 64 KiB
    size_t slots_bytes = (size_t)N_SEG * CAP * sizeof(unsigned short); // 1 MiB
    size_t need = counts_bytes + slots_bytes;

    if (ws_size < need) {
        hipMemsetAsync(d_out, 0, (size_t)out_size * sizeof(float), stream);
        combine_scatter_add<<<2048, 256, 0, stream>>>(data, tags, out, total);
        return;
    }

    int* counts = (int*)d_ws;
    unsigned short* slots = (unsigned short*)((char*)d_ws + counts_bytes);

    hipMemsetAsync(counts, 0, counts_bytes, stream);

    hist_fill<<<(n_rows + 255) / 256, 256, 0, stream>>>(tags, n_rows, counts, slots);

    gather_sum<<<N_SEG, 256, 0, stream>>>(data, tags, counts, slots, out, n_rows);
}